// Round 14
// baseline (119.081 us; speedup 1.0000x reference)
//
#include <hip/hip_runtime.h>

typedef __attribute__((ext_vector_type(8))) short short8;
typedef __attribute__((ext_vector_type(8))) _Float16 half8;
typedef __attribute__((ext_vector_type(4))) float floatx4;
typedef __attribute__((ext_vector_type(4))) float floatv4;
typedef __attribute__((ext_vector_type(4))) short short4v;
typedef __attribute__((ext_vector_type(4))) unsigned short ushort4v;
typedef unsigned short u16;

#define MFMA_BF16(a,b,c) __builtin_amdgcn_mfma_f32_16x16x32_bf16((a),(b),(c),0,0,0)
#define MFMA_F16(a,b,c)  __builtin_amdgcn_mfma_f32_16x16x32_f16((a),(b),(c),0,0,0)

__device__ __forceinline__ u16 f2bf(float f) {
    union { float f; unsigned u; } v; v.f = f;
    unsigned r = (v.u + 0x7fffu + ((v.u >> 16) & 1u)) >> 16;
    return (u16)r;
}
__device__ __forceinline__ float bf2f(u16 h) {
    union { unsigned u; float f; } v; v.u = ((unsigned)h) << 16;
    return v.f;
}
__device__ __forceinline__ u16 f2h(float f) {
    union { _Float16 h; u16 u; } v; v.h = (_Float16)f;
    return v.u;
}

__device__ __forceinline__ void gll16(const u16* g, u16* l) {
    __builtin_amdgcn_global_load_lds(
        (const __attribute__((address_space(1))) void*)g,
        (__attribute__((address_space(3))) void*)l, 16, 0, 0);
}

// ---------------------------------------------------------------------------
// prep_kernel: sniff + x -> xT f16 (transpose) + W -> f16 stacked Wall[1536][512]
// + Wo16. Vectorized 4x.
// ---------------------------------------------------------------------------
__global__ __launch_bounds__(256) void prep_kernel(
    const void* __restrict__ x,
    const void* __restrict__ Wq, const void* __restrict__ Wk,
    const void* __restrict__ Wv, const void* __restrict__ Wo,
    u16* __restrict__ xT, u16* __restrict__ Wall, u16* __restrict__ Wo16,
    int* __restrict__ flag)
{
    __shared__ float tile[64][65];
    __shared__ int sflag;
    const int tid = threadIdx.x;

    if (tid < 64) {
        u16 u = ((const u16*)x)[2 * tid];
        int e = (u >> 7) & 0xFF;
        unsigned long long m = __ballot(e >= 96 && e <= 140);
        if (tid == 0) sflag = (__popcll(m) >= 40) ? 0 : 1;
    }
    __syncthreads();
    const int isf32 = sflag;
    const int bid = blockIdx.x;
    if (bid == 0 && tid == 0) *flag = isf32;

    if (bid < 512) {
        const int b = bid >> 7, rem = bid & 127;
        const int c0 = (rem >> 4) * 64, n0 = (rem & 15) * 64;
        const int cr = tid >> 4;
        const int n4 = (tid & 15) * 4;
        const size_t base = (size_t)b * 512 * 1024;
        #pragma unroll
        for (int i = 0; i < 4; ++i) {
            int c = i * 16 + cr;
            size_t idx = base + (size_t)(c0 + c) * 1024 + n0 + n4;
            float v0, v1, v2, v3;
            if (isf32) {
                floatv4 v = *(const floatv4*)((const float*)x + idx);
                v0 = v[0]; v1 = v[1]; v2 = v[2]; v3 = v[3];
            } else {
                ushort4v u = *(const ushort4v*)((const u16*)x + idx);
                v0 = bf2f(u[0]); v1 = bf2f(u[1]); v2 = bf2f(u[2]); v3 = bf2f(u[3]);
            }
            tile[c][n4 + 0] = v0; tile[c][n4 + 1] = v1;
            tile[c][n4 + 2] = v2; tile[c][n4 + 3] = v3;
        }
        __syncthreads();
        const int nr = tid >> 4;
        const int c4 = (tid & 15) * 4;
        #pragma unroll
        for (int i = 0; i < 4; ++i) {
            int n = i * 16 + nr;
            short4v o;
            o[0] = (short)f2h(tile[c4 + 0][n]);
            o[1] = (short)f2h(tile[c4 + 1][n]);
            o[2] = (short)f2h(tile[c4 + 2][n]);
            o[3] = (short)f2h(tile[c4 + 3][n]);
            *(short4v*)(xT + ((size_t)b * 1024 + n0 + n) * 512 + c0 + c4) = o;
        }
    } else {
        const int b2 = bid - 512;
        #pragma unroll
        for (int m = 0; m < 4; ++m) {
            const void* src = (m == 0) ? Wq : (m == 1) ? Wk : (m == 2) ? Wv : Wo;
            u16* dst = (m == 3) ? Wo16 : (Wall + m * 262144);
            #pragma unroll
            for (int j = 0; j < 4; ++j) {
                int i = b2 * 4096 + j * 1024 + tid * 4;
                short4v o;
                if (isf32) {
                    floatv4 v = *(const floatv4*)((const float*)src + i);
                    o[0] = (short)f2h(v[0]); o[1] = (short)f2h(v[1]);
                    o[2] = (short)f2h(v[2]); o[3] = (short)f2h(v[3]);
                } else {
                    ushort4v u = *(const ushort4v*)((const u16*)src + i);
                    o[0] = (short)f2h(bf2f(u[0])); o[1] = (short)f2h(bf2f(u[1]));
                    o[2] = (short)f2h(bf2f(u[2])); o[3] = (short)f2h(bf2f(u[3]));
                }
                *(short4v*)(dst + i) = o;
            }
        }
    }
}

// ---------------------------------------------------------------------------
// gemm64: 64(M) x 128(N) f16 GEMM, K=512, BK=64 (8 barriers), dbuf.
// Buffer (12288 shorts = 24 KB): A chunks 0-7 (kh=idx>>2, rg=idx&3),
// B chunks 8-23 (ib=idx-8, kh=ib>>3, rg=ib&7). Substep-s frags:
// A @ s*2048 + m*32, B @ 4096 + s*4096 + n*32 (+pA swizzle).
// ---------------------------------------------------------------------------
__device__ __forceinline__ void stage64(
    const u16* __restrict__ A, const u16* __restrict__ B,
    u16* L, int k0, int wave, int srow, int koff)
{
    #pragma unroll
    for (int i = 0; i < 6; ++i) {
        int idx = wave + i * 4;
        const u16* s;
        if (idx < 8) {
            int kh = idx >> 2, rg = idx & 3;
            s = A + (rg * 16 + srow) * 512 + k0 + kh * 32 + koff;
        } else {
            int ib = idx - 8, kh = ib >> 3, rg = ib & 7;
            s = B + (rg * 16 + srow) * 512 + k0 + kh * 32 + koff;
        }
        gll16(s, L + idx * 512);
    }
}

__device__ __forceinline__ void gemm64(
    const u16* __restrict__ A, const u16* __restrict__ B,
    u16* lds, floatx4 acc[2][4], int lane, int wave)
{
    const int quad = lane >> 4, l16 = lane & 15;
    const int msub = (wave & 1) * 32, nsub = (wave >> 1) * 64;
    const int srow = lane >> 2;
    const int koff = (((lane & 3) - (srow >> 1)) & 3) * 8;
    const int pA = ((quad + (l16 >> 1)) & 3) * 8;

    stage64(A, B, lds, 0, wave, srow, koff);
    for (int k0 = 0; k0 < 512; k0 += 64) {
        __syncthreads();
        u16* L = lds + ((k0 >> 6) & 1) * 12288;
        if (k0 + 64 < 512)
            stage64(A, B, lds + (((k0 >> 6) + 1) & 1) * 12288,
                    k0 + 64, wave, srow, koff);

        #pragma unroll
        for (int s = 0; s < 2; ++s) {
            half8 ah[2], bh[4];
            #pragma unroll
            for (int mt = 0; mt < 2; ++mt)
                ah[mt] = *(const half8*)(L + s * 2048 + (msub + mt * 16 + l16) * 32 + pA);
            #pragma unroll
            for (int nt = 0; nt < 4; ++nt)
                bh[nt] = *(const half8*)(L + 4096 + s * 4096 + (nsub + nt * 16 + l16) * 32 + pA);
            #pragma unroll
            for (int mt = 0; mt < 2; ++mt)
                #pragma unroll
                for (int nt = 0; nt < 4; ++nt)
                    acc[mt][nt] = MFMA_F16(ah[mt], bh[nt], acc[mt][nt]);
        }
    }
}

// ---------------------------------------------------------------------------
// proj_kernel: unified q/k/v, A = Wall rows (o as M), B = xT rows.
// Grid (32 n-tiles, 24 o-tiles) = 768 blocks, 3/CU, LDS 48 KB.
// ---------------------------------------------------------------------------
__global__ __launch_bounds__(256) void proj_kernel(
    const u16* __restrict__ xT, const u16* __restrict__ Wall,
    u16* __restrict__ qT, u16* __restrict__ kT,
    u16* __restrict__ vbuf)
{
    __shared__ u16 lds[24576];   // 48 KB
    const int lane = threadIdx.x & 63;
    const int wave = threadIdx.x >> 6;
    const int quad = lane >> 4, l16 = lane & 15;
    const int m0 = blockIdx.x * 128;      // stacked (b,n)
    const int oblk = blockIdx.y * 64;     // o in 0..1535
    const int msub = (wave & 1) * 32, nsub = (wave >> 1) * 64;

    floatx4 acc[2][4];
    #pragma unroll
    for (int i = 0; i < 2; ++i)
        #pragma unroll
        for (int j = 0; j < 4; ++j) acc[i][j] = (floatx4){0.f, 0.f, 0.f, 0.f};

    gemm64(Wall + (size_t)oblk * 512, xT + (size_t)m0 * 512, lds, acc, lane, wave);

    if (oblk < 1024) {
        u16* dst = (oblk < 512) ? qT : kT;
        #pragma unroll
        for (int mt = 0; mt < 2; ++mt) {
            int od = (oblk & 511) + msub + mt * 16 + quad * 4;   // head*64 + dd0
            int hsub = od >> 6, dd0 = od & 63;
            #pragma unroll
            for (int nt = 0; nt < 4; ++nt) {
                int col = m0 + nsub + nt * 16 + l16;
                int b = col >> 10, n = col & 1023;
                short4v o4;
                #pragma unroll
                for (int r = 0; r < 4; ++r) o4[r] = (short)f2h(acc[mt][nt][r]);
                *(short4v*)(dst + ((size_t)(b * 8 + hsub) * 1024 + n) * 64 + dd0) = o4;
            }
        }
    } else {
        #pragma unroll
        for (int mt = 0; mt < 2; ++mt)
            #pragma unroll
            for (int r = 0; r < 4; ++r) {
                int o = (oblk - 1024) + msub + mt * 16 + quad * 4 + r;
                #pragma unroll
                for (int nt = 0; nt < 4; ++nt) {
                    int col = m0 + nsub + nt * 16 + l16;
                    int b = col >> 10, n = col & 1023;
                    vbuf[b * 524288 + o * 1024 + n] = f2bf(acc[mt][nt][r]);
                }
            }
    }
}

// ---------------------------------------------------------------------------
// attn_kernel: 256 threads (4 waves = 64 q), grid (head=32, qtile=16) = 512
// blocks = 2/CU. j-step 128 keys (8 barriers): buffer = K[128][64] f16
// (chunks 0-15: kc=idx>>3, rg=idx&7) + V[64][128] bf16 (chunks 16-31:
// js=v>>2, rg=v&3). dbuf 64 KB. S^T formulation, P^T via shuffles.
// ---------------------------------------------------------------------------
__global__ __launch_bounds__(256) void attn_kernel(
    const u16* __restrict__ qT, const u16* __restrict__ kT,
    const u16* __restrict__ vbuf,
    u16* __restrict__ yT)
{
    __shared__ u16 lds[32768];   // 64 KB
    const int lane = threadIdx.x & 63;
    const int wave = threadIdx.x >> 6;      // 0..3
    const int quad = lane >> 4, l16 = lane & 15;
    const int head = blockIdx.x;
    const int i0 = blockIdx.y * 64 + wave * 16;
    const int b = head >> 3, h = head & 7;
    const u16* qp = qT + head * 65536;
    const u16* kp = kT + head * 65536;
    const u16* vb = vbuf + b * 524288 + h * 65536;
    const int srow = lane >> 2;
    const int koff = (((lane & 3) - (srow >> 1)) & 3) * 8;
    const int pA = ((quad + (l16 >> 1)) & 3) * 8;

    const int qoff = (i0 + l16) * 64 + quad * 8;
    half8 aq0 = *(const half8*)(qp + qoff);
    half8 aq1 = *(const half8*)(qp + qoff + 32);

    float lsum = 0.f;
    floatx4 oacc[4];
    #pragma unroll
    for (int dt = 0; dt < 4; ++dt) oacc[dt] = (floatx4){0.f, 0.f, 0.f, 0.f};

    const float L2E = 1.44269504f;
    const float C2  = 69.2493619f;   // 48 * log2(e)

    auto stage_kv = [&](int j0, u16* L) {
        #pragma unroll
        for (int i = 0; i < 8; ++i) {
            int c = wave + i * 4;
            const u16* s;
            if (c < 16) {
                int kc = c >> 3, rg = c & 7;
                s = kp + (j0 + rg * 16 + srow) * 64 + kc * 32 + koff;
            } else {
                int v = c - 16, js = v >> 2, rg = v & 3;
                s = vb + (rg * 16 + srow) * 1024 + j0 + js * 32 + koff;
            }
            gll16(s, L + c * 512);
        }
    };

    stage_kv(0, lds);

    const int srcA = (quad & 1) * 32 + l16;
    const int srcB = srcA + 16;
    const bool hi = (quad >> 1) != 0;

    for (int j0 = 0; j0 < 1024; j0 += 128) {
        __syncthreads();
        u16* L = lds + ((j0 >> 7) & 1) * 16384;
        if (j0 + 128 < 1024)
            stage_kv(j0 + 128, lds + (((j0 >> 7) + 1) & 1) * 16384);

        #pragma unroll
        for (int hf = 0; hf < 2; ++hf) {
            unsigned pk[4][2];
            #pragma unroll
            for (int jt = 0; jt < 4; ++jt) {
                int off = hf * 2048 + jt * 512 + l16 * 32 + pA;
                half8 kh0 = *(const half8*)(L + off);
                half8 kh1 = *(const half8*)(L + 4096 + off);
                floatx4 s = {0.f, 0.f, 0.f, 0.f};
                s = MFMA_F16(kh0, aq0, s);
                s = MFMA_F16(kh1, aq1, s);
                float p0 = __builtin_amdgcn_exp2f(s[0] * L2E - C2);
                float p1 = __builtin_amdgcn_exp2f(s[1] * L2E - C2);
                float p2 = __builtin_amdgcn_exp2f(s[2] * L2E - C2);
                float p3 = __builtin_amdgcn_exp2f(s[3] * L2E - C2);
                lsum += (p0 + p1) + (p2 + p3);
                pk[jt][0] = (unsigned)f2bf(p0) | ((unsigned)f2bf(p1) << 16);
                pk[jt][1] = (unsigned)f2bf(p2) | ((unsigned)f2bf(p3) << 16);
            }

            #pragma unroll
            for (int jc = 0; jc < 2; ++jc) {
                unsigned a0 = (unsigned)__shfl((int)pk[jc * 2][0], srcA);
                unsigned b0 = (unsigned)__shfl((int)pk[jc * 2 + 1][0], srcA);
                unsigned a1 = (unsigned)__shfl((int)pk[jc * 2][1], srcA);
                unsigned b1 = (unsigned)__shfl((int)pk[jc * 2 + 1][1], srcA);
                unsigned a2 = (unsigned)__shfl((int)pk[jc * 2][0], srcB);
                unsigned b2 = (unsigned)__shfl((int)pk[jc * 2 + 1][0], srcB);
                unsigned a3 = (unsigned)__shfl((int)pk[jc * 2][1], srcB);
                unsigned b3 = (unsigned)__shfl((int)pk[jc * 2 + 1][1], srcB);
                union { unsigned u[4]; short8 s8; } pu;
                pu.u[0] = hi ? b0 : a0;
                pu.u[1] = hi ? b1 : a1;
                pu.u[2] = hi ? b2 : a2;
                pu.u[3] = hi ? b3 : a3;
                short8 pfrag = pu.s8;
                #pragma unroll
                for (int dt = 0; dt < 4; ++dt) {
                    int off = (hf * 2 + jc) * 2048 + dt * 512 + l16 * 32 + pA;
                    short8 vv = *(const short8*)(L + 8192 + off);
                    oacc[dt] = MFMA_BF16(vv, pfrag, oacc[dt]);
                }
            }
        }
    }

    lsum += __shfl_xor(lsum, 16);
    lsum += __shfl_xor(lsum, 32);
    const float linv = 1.0f / lsum;

    u16* yrow = yT + ((size_t)b * 1024 + i0 + l16) * 512 + h * 64;
    #pragma unroll
    for (int dt = 0; dt < 4; ++dt) {
        short4v o;
        #pragma unroll
        for (int r = 0; r < 4; ++r) o[r] = (short)f2h(oacc[dt][r] * linv);
        *(short4v*)(yrow + dt * 16 + quad * 4) = o;
    }
}

// ---------------------------------------------------------------------------
// out_kernel: Wo(f16) @ yT(f16), 64(o) x 64(b,n) tiles, BK=64, dbuf 32 KB.
// Grid (64 ntiles, 8 otiles) = 512 blocks = 2/CU, 8 barriers.
// Buffer (8192 shorts): A chunks 0-7 (kh=idx>>2, rg=idx&3),
// B chunks 8-15 (ib=idx-8, kh=ib>>2, rg=ib&3).
// ---------------------------------------------------------------------------
__global__ __launch_bounds__(256) void out_kernel(
    const u16* __restrict__ Woh, const u16* __restrict__ yT,
    void* __restrict__ out, const int* __restrict__ flag)
{
    __shared__ u16 lds[16384];   // 32 KB
    const int isf32 = *flag;
    const int lane = threadIdx.x & 63;
    const int wave = threadIdx.x >> 6;
    const int quad = lane >> 4, l16 = lane & 15;
    const int nblk = blockIdx.x * 64;    // stacked (b,n)
    const int oblk = blockIdx.y * 64;    // o
    const u16* A = Woh + (size_t)oblk * 512;
    const u16* B = yT + (size_t)nblk * 512;
    const int msub = (wave & 1) * 32, nsub = (wave >> 1) * 32;
    const int srow = lane >> 2;
    const int koff = (((lane & 3) - (srow >> 1)) & 3) * 8;
    const int pA = ((quad + (l16 >> 1)) & 3) * 8;

    floatx4 acc[2][2];
    #pragma unroll
    for (int i = 0; i < 2; ++i)
        #pragma unroll
        for (int j = 0; j < 2; ++j) acc[i][j] = (floatx4){0.f, 0.f, 0.f, 0.f};

    auto stage = [&](int k0, u16* L) {
        #pragma unroll
        for (int i = 0; i < 4; ++i) {
            int idx = wave + i * 4;
            const u16* s;
            if (idx < 8) {
                int kh = idx >> 2, rg = idx & 3;
                s = A + (rg * 16 + srow) * 512 + k0 + kh * 32 + koff;
            } else {
                int ib = idx - 8, kh = ib >> 2, rg = ib & 3;
                s = B + (rg * 16 + srow) * 512 + k0 + kh * 32 + koff;
            }
            gll16(s, L + idx * 512);
        }
    };

    stage(0, lds);
    for (int k0 = 0; k0 < 512; k0 += 64) {
        __syncthreads();
        u16* L = lds + ((k0 >> 6) & 1) * 8192;
        if (k0 + 64 < 512)
            stage(k0 + 64, lds + (((k0 >> 6) + 1) & 1) * 8192);

        #pragma unroll
        for (int s = 0; s < 2; ++s) {
            half8 ah[2], bh[2];
            #pragma unroll
            for (int mt = 0; mt < 2; ++mt)
                ah[mt] = *(const half8*)(L + s * 2048 + (msub + mt * 16 + l16) * 32 + pA);
            #pragma unroll
            for (int nt = 0; nt < 2; ++nt)
                bh[nt] = *(const half8*)(L + 4096 + s * 2048 + (nsub + nt * 16 + l16) * 32 + pA);
            #pragma unroll
            for (int mt = 0; mt < 2; ++mt)
                #pragma unroll
                for (int nt = 0; nt < 2; ++nt)
                    acc[mt][nt] = MFMA_F16(ah[mt], bh[nt], acc[mt][nt]);
        }
    }

    #pragma unroll
    for (int mt = 0; mt < 2; ++mt)
        #pragma unroll
        for (int r = 0; r < 4; ++r) {
            int o = oblk + msub + mt * 16 + quad * 4 + r;
            #pragma unroll
            for (int nt = 0; nt < 2; ++nt) {
                int col = nblk + nsub + nt * 16 + l16;
                int b = col >> 10, n = col & 1023;
                size_t di = (size_t)b * 524288 + o * 1024 + n;
                if (isf32) ((float*)out)[di] = acc[mt][nt][r];
                else       ((u16*)out)[di] = f2bf(acc[mt][nt][r]);
            }
        }
}

extern "C" void kernel_launch(void* const* d_in, const int* in_sizes, int n_in,
                              void* d_out, int out_size, void* d_ws, size_t ws_size,
                              hipStream_t stream)
{
    const void* x  = d_in[0];
    const void* Wq = d_in[1];
    const void* Wk = d_in[2];
    const void* Wv = d_in[3];
    const void* Wo = d_in[4];

    const int NX = 4 * 512 * 1024;
    const int NW = 512 * 512;

    char* p = (char*)d_ws;
    int* flag = (int*)p; p += 64;
    u16* xT   = (u16*)p; p += (size_t)NX * 2;
    u16* Wall = (u16*)p; p += (size_t)NW * 3 * 2;
    u16* Woh  = (u16*)p; p += (size_t)NW * 2;
    u16* qT   = (u16*)p; p += (size_t)NX * 2;
    u16* kT   = (u16*)p; p += (size_t)NX * 2;
    u16* vbuf = (u16*)p; p += (size_t)NX * 2;
    u16* ybuf = (u16*)p; p += (size_t)NX * 2;

    prep_kernel<<<576, 256, 0, stream>>>(
        x, Wq, Wk, Wv, Wo, xT, Wall, Woh, flag);
    proj_kernel<<<dim3(32, 24), 256, 0, stream>>>(
        xT, Wall, qT, kT, vbuf);
    attn_kernel<<<dim3(32, 16), 256, 0, stream>>>(
        qT, kT, vbuf, ybuf);
    out_kernel<<<dim3(64, 8), 256, 0, stream>>>(
        Woh, ybuf, d_out, flag);
}